// Round 1
// baseline (177.337 us; speedup 1.0000x reference)
//
#include <hip/hip_runtime.h>
#include <climits>

// RandomCutout: B=32, H=512, W=512, C=3 fp32, 2 masks of 128x128 per image.
// out[b,y,x,c] = in[b,y,x,c] unless (y,x) in any clipped mask rect, else 0.
//
// Layout: one block per image row (grid = B*H = 16384). b and y are
// block-uniform -> center loads become scalar loads, the y-test is a scalar
// compare, and rows with no mask overlap take a uniform pure-copy path.
//
// Column test with NO divides: cut columns [x1,x2) <=> flat float offset
// p in [3*x1, 3*x2) exactly (p = 3*xc + c, c in {0,1,2}). Unclipped bounds
// are equivalent within p in [0,1536): negative lower bound -> always true,
// upper bound > 1535 -> always true. Inactive mask -> empty interval
// (upper bound = INT_MIN).

#define BB 32
#define HH 512
#define WW 512
#define ROW4 384          // float4 per row: 512*3/4
#define HALF 64           // MASK/2

__global__ __launch_bounds__(128)
void RandomCutout_59545426592097_kernel(const float4* __restrict__ in,
                                        const int* __restrict__ cys,
                                        const int* __restrict__ cxs,
                                        float4* __restrict__ out) {
    const int row  = blockIdx.x;          // b * 512 + y
    const int b    = row >> 9;            // uniform -> SGPR
    const int y    = row & (HH - 1);      // uniform -> SGPR
    const int base = row * ROW4;
    const int t    = threadIdx.x;         // [0,128)

    const float4* __restrict__ src = in + base;
    float4* __restrict__ dst       = out + base;

    // Payload: 3 float4 per thread, stride 128 (fully coalesced).
    float4 v0 = src[t];
    float4 v1 = src[t + 128];
    float4 v2 = src[t + 256];

    // Uniform per-image mask parameters (scalar loads).
    const int cy0 = cys[2 * b + 0];
    const int cy1 = cys[2 * b + 1];
    const bool yin_a = (y >= cy0 - HALF) & (y < cy0 + HALF);
    const bool yin_b = (y >= cy1 - HALF) & (y < cy1 + HALF);

    if (yin_a | yin_b) {                  // uniform branch: ~55% of rows skip
        const int cx0 = cxs[2 * b + 0];
        const int cx1 = cxs[2 * b + 1];
        // Float-offset cut intervals [3*(cx-64), 3*(cx+64)); empty if y-miss.
        const int A1 = 3 * (cx0 - HALF);
        const int A2 = yin_a ? 3 * (cx0 + HALF) : INT_MIN;
        const int B1 = 3 * (cx1 - HALF);
        const int B2 = yin_b ? 3 * (cx1 + HALF) : INT_MIN;

        const int p0 = t * 4;             // flat float offset of v0.x in row
        const int p1 = (t + 128) * 4;
        const int p2 = (t + 256) * 4;

#define CUT(p) ((((p) >= A1) & ((p) < A2)) | (((p) >= B1) & ((p) < B2)))
        if (CUT(p0 + 0)) v0.x = 0.0f;
        if (CUT(p0 + 1)) v0.y = 0.0f;
        if (CUT(p0 + 2)) v0.z = 0.0f;
        if (CUT(p0 + 3)) v0.w = 0.0f;

        if (CUT(p1 + 0)) v1.x = 0.0f;
        if (CUT(p1 + 1)) v1.y = 0.0f;
        if (CUT(p1 + 2)) v1.z = 0.0f;
        if (CUT(p1 + 3)) v1.w = 0.0f;

        if (CUT(p2 + 0)) v2.x = 0.0f;
        if (CUT(p2 + 1)) v2.y = 0.0f;
        if (CUT(p2 + 2)) v2.z = 0.0f;
        if (CUT(p2 + 3)) v2.w = 0.0f;
#undef CUT
    }

    dst[t]       = v0;
    dst[t + 128] = v1;
    dst[t + 256] = v2;
}

extern "C" void kernel_launch(void* const* d_in, const int* in_sizes, int n_in,
                              void* d_out, int out_size, void* d_ws, size_t ws_size,
                              hipStream_t stream) {
    const float4* in  = (const float4*)d_in[0];
    const int*    cys = (const int*)d_in[1];
    const int*    cxs = (const int*)d_in[2];
    float4*       out = (float4*)d_out;

    const int threads = 128;
    const int blocks  = BB * HH;          // 16384, one block per image row
    RandomCutout_59545426592097_kernel<<<blocks, threads, 0, stream>>>(in, cys, cxs, out);
}